// Round 5
// baseline (343.800 us; speedup 1.0000x reference)
//
#include <hip/hip_runtime.h>
#include <math.h>

#define NN 50000
#define NE 800000

typedef __attribute__((ext_vector_type(8))) short short8;
typedef __attribute__((ext_vector_type(4))) float floatx4;

#define AS1 __attribute__((address_space(1)))
#define AS3 __attribute__((address_space(3)))

__device__ __forceinline__ unsigned short f2bf(float f) {
    unsigned u = __float_as_uint(f);
    unsigned r = (u + 0x7fff + ((u >> 16) & 1)) >> 16;
    return (unsigned short)r;
}
__device__ __forceinline__ float bf2f(unsigned short h) {
    return __uint_as_float(((unsigned)h) << 16);
}

// ---------------- CSR build ----------------

__global__ void k_hist(const int* __restrict__ dst, int* __restrict__ deg) {
    int e = blockIdx.x * blockDim.x + threadIdx.x;
    if (e < NE) atomicAdd(&deg[dst[e]], 1);
}

__global__ void k_scan_part(const int* __restrict__ deg, int* __restrict__ partials) {
    __shared__ int s[1024];
    int idx = blockIdx.x * 1024 + threadIdx.x;
    s[threadIdx.x] = (idx < NN) ? deg[idx] : 0;
    for (int off = 512; off > 0; off >>= 1) {
        __syncthreads();
        if (threadIdx.x < off) s[threadIdx.x] += s[threadIdx.x + off];
    }
    if (threadIdx.x == 0) partials[blockIdx.x] = s[0];
}

// single wave: prefix-scan up to 64 partials
__global__ void k_scan_top(int* __restrict__ partials, int* __restrict__ row_start, int n) {
    int lane = threadIdx.x;
    int orig = (lane < n) ? partials[lane] : 0;
    int v = orig;
    for (int off = 1; off < 64; off <<= 1) {
        int u = __shfl_up(v, off, 64);
        if (lane >= off) v += u;
    }
    if (lane < n) partials[lane] = v - orig;   // exclusive
    if (lane == 63) row_start[NN] = v;         // grand total
}

__global__ void k_scan_final(const int* __restrict__ deg, const int* __restrict__ partials,
                             int* __restrict__ row_start) {
    __shared__ int s[1024];
    int idx = blockIdx.x * 1024 + threadIdx.x;
    int v = (idx < NN) ? deg[idx] : 0;
    s[threadIdx.x] = v;
    for (int off = 1; off < 1024; off <<= 1) {
        __syncthreads();
        int tmp = (threadIdx.x >= off) ? s[threadIdx.x - off] : 0;
        __syncthreads();
        s[threadIdx.x] += tmp;
    }
    if (idx < NN) row_start[idx] = partials[blockIdx.x] + s[threadIdx.x] - v;
}

__global__ void k_scatter(const int* __restrict__ src, const int* __restrict__ dst,
                          const int* __restrict__ row_start, int* __restrict__ cursor,
                          int* __restrict__ col_idx) {
    int e = blockIdx.x * blockDim.x + threadIdx.x;
    if (e < NE) {
        int d = dst[e];
        int slot = atomicAdd(&cursor[d], 1);
        col_idx[row_start[d] + slot] = src[e];
    }
}

// ---------------- f32 -> bf16 convert ----------------

__global__ __launch_bounds__(256)
void k_cvt(const float* __restrict__ src, unsigned short* __restrict__ dst) {
    int i = (blockIdx.x * 256 + threadIdx.x) * 8;
    float4 a = *(const float4*)&src[i];
    float4 b = *(const float4*)&src[i + 4];
    short8 v;
    v[0] = (short)f2bf(a.x); v[1] = (short)f2bf(a.y);
    v[2] = (short)f2bf(a.z); v[3] = (short)f2bf(a.w);
    v[4] = (short)f2bf(b.x); v[5] = (short)f2bf(b.y);
    v[6] = (short)f2bf(b.z); v[7] = (short)f2bf(b.w);
    *(short8*)&dst[i] = v;
}

// ---------------- pack W (f32 [128][128]) into MFMA-B bf16 layout ----------------

__global__ __launch_bounds__(256)
void k_packW(const float* w0, const float* w1, const float* w2, const float* w3,
             const float* w4, const float* w5, const float* w6, const float* w7,
             short* __restrict__ wpk) {
    const float* W;
    switch (blockIdx.x) {
        case 0: W = w0; break; case 1: W = w1; break;
        case 2: W = w2; break; case 3: W = w3; break;
        case 4: W = w4; break; case 5: W = w5; break;
        case 6: W = w6; break; default: W = w7; break;
    }
    short* dst = wpk + (size_t)blockIdx.x * 16384;
#pragma unroll
    for (int i = 0; i < 8; ++i) {
        int q = threadIdx.x + i * 256;
        int cb = q >> 8, ks = (q >> 6) & 3, lane = q & 63;
        int n = lane & 15, g = lane >> 4;
        int col = cb * 16 + n, krow = ks * 32 + g * 8;
        short8 v;
#pragma unroll
        for (int j = 0; j < 8; ++j)
            v[j] = (short)f2bf(W[(krow + j) * 128 + col]);
        *(short8*)&dst[q * 8] = v;
    }
}

// ---------------- mean aggregation (wave per node, bf16 feats) ----------------

__global__ __launch_bounds__(256)
void k_agg(const unsigned short* __restrict__ feat, const int* __restrict__ row_start,
           const int* __restrict__ col_idx, unsigned short* __restrict__ outp) {
    int node = (blockIdx.x * 256 + threadIdx.x) >> 6;
    int lane = threadIdx.x & 63;
    if (node >= NN) return;
    const int beg = row_start[node], end = row_start[node + 1];
    const size_t lo = (size_t)(lane * 2);
    float sx = 0.f, sy = 0.f;
    int j = beg;
#pragma unroll 1
    for (; j + 8 <= end; j += 8) {
        int s[8];
#pragma unroll
        for (int u = 0; u < 8; ++u) s[u] = col_idx[j + u];
        unsigned v[8];
#pragma unroll
        for (int u = 0; u < 8; ++u)
            v[u] = *(const unsigned*)&feat[(size_t)s[u] * 128 + lo];
#pragma unroll
        for (int u = 0; u < 8; ++u) {
            sx += bf2f((unsigned short)(v[u] & 0xffff));
            sy += bf2f((unsigned short)(v[u] >> 16));
        }
    }
#pragma unroll 1
    for (; j < end; ++j) {
        int s = col_idx[j];
        unsigned v = *(const unsigned*)&feat[(size_t)s * 128 + lo];
        sx += bf2f((unsigned short)(v & 0xffff));
        sy += bf2f((unsigned short)(v >> 16));
    }
    float inv = 1.0f / fmaxf((float)(end - beg), 1.0f);
    unsigned o = (unsigned)f2bf(sx * inv) | ((unsigned)f2bf(sy * inv) << 16);
    *(unsigned*)&outp[(size_t)node * 128 + lo] = o;
}

// ---------------- fused MFMA GEMM helpers ----------------
// tile 128 rows x 128 cols per 256-thr block; wave = 32 rows (2 frags).
// LDS A layout: row r, k-chunk c stored at slot c^(r&7): sA[(r*16+slot)*8 + j]

__device__ __forceinline__ void stage_w(const short* Wc, short* sW, int wv, int lane) {
#pragma unroll
    for (int i = 0; i < 8; ++i) {
        int cbase = (i * 4 + wv) * 64;
        __builtin_amdgcn_global_load_lds(
            (const AS1 unsigned int*)(Wc + (size_t)(cbase + lane) * 8),
            (AS3 unsigned int*)(sW + cbase * 8), 16, 0, 0);
    }
}

__device__ __forceinline__ void stage_a(const unsigned short* Ac, short* sA, int row0,
                                        int wv, int lane) {
#pragma unroll
    for (int i = 0; i < 8; ++i) {
        int cbase = (i * 4 + wv) * 64;
        int id = cbase + lane;
        int r = id >> 4, cs = id & 15;
        int rg = row0 + r; if (rg >= NN) rg = NN - 1;
        int csrc = cs ^ (r & 7);
        __builtin_amdgcn_global_load_lds(
            (const AS1 unsigned int*)(Ac + (size_t)rg * 128 + csrc * 8),
            (AS3 unsigned int*)(sA + cbase * 8), 16, 0, 0);
    }
}

__device__ __forceinline__ void drain_barrier() {
    asm volatile("s_waitcnt vmcnt(0)" ::: "memory");
    __builtin_amdgcn_sched_barrier(0);
    __syncthreads();
}

__device__ __forceinline__ void mm_tile(const short* sA, const short* sW, int wv, int lane,
                                        floatx4 acc0[8], floatx4 acc1[8]) {
    const int m = lane & 15, g = lane >> 4;
    const int r0 = wv * 32;
#pragma unroll
    for (int ks = 0; ks < 4; ++ks) {
        int cxor = (ks * 4 + g) ^ (m & 7);
        short8 af0 = *(const short8*)&sA[((r0 + m) * 16 + cxor) * 8];
        short8 af1 = *(const short8*)&sA[((r0 + 16 + m) * 16 + cxor) * 8];
#pragma unroll
        for (int cb = 0; cb < 8; ++cb) {
            short8 bf = *(const short8*)&sW[((cb * 4 + ks) * 64 + lane) * 8];
            acc0[cb] = __builtin_amdgcn_mfma_f32_16x16x32_bf16(af0, bf, acc0[cb], 0, 0, 0);
            acc1[cb] = __builtin_amdgcn_mfma_f32_16x16x32_bf16(af1, bf, acc1[cb], 0, 0, 0);
        }
    }
}

// bias + ELU on acc, write bf16 into sA in A-frag layout (wave-local rows), zero acc
__device__ __forceinline__ void act_to_lds(short* sA, const float* bias, int wv, int lane,
                                           floatx4 acc0[8], floatx4 acc1[8]) {
    const int m = lane & 15, g = lane >> 4;
    float bb[8];
#pragma unroll
    for (int cb = 0; cb < 8; ++cb) bb[cb] = bias[cb * 16 + m];
#pragma unroll
    for (int f = 0; f < 2; ++f) {
#pragma unroll
        for (int cb = 0; cb < 8; ++cb) {
            int C = cb * 16 + m;
            int chunk = C >> 3, within = C & 7;
#pragma unroll
            for (int rr = 0; rr < 4; ++rr) {
                int Rl = wv * 32 + f * 16 + g * 4 + rr;
                float v = (f ? acc1[cb][rr] : acc0[cb][rr]) + bb[cb];
                v = (v > 0.f) ? v : expm1f(v);
                int slot = chunk ^ (Rl & 7);
                sA[(Rl * 16 + slot) * 8 + within] = (short)f2bf(v);
            }
        }
    }
#pragma unroll
    for (int cb = 0; cb < 8; ++cb) {
        acc0[cb] = (floatx4){0.f, 0.f, 0.f, 0.f};
        acc1[cb] = (floatx4){0.f, 0.f, 0.f, 0.f};
    }
}

#define ACC_INIT \
    floatx4 acc0[8], acc1[8]; \
    _Pragma("unroll") \
    for (int cb = 0; cb < 8; ++cb) { \
        acc0[cb] = (floatx4){0.f, 0.f, 0.f, 0.f}; \
        acc1[cb] = (floatx4){0.f, 0.f, 0.f, 0.f}; \
    }

// ---------------- fused kernels ----------------

// h_skip = ELU(h@W1+b1)@W2+b2, stored bf16 IN-PLACE over hB (block-local rows only)
__global__ __launch_bounds__(256)
void k_skip(unsigned short* __restrict__ hB, const short* __restrict__ Wp1,
            const short* __restrict__ Wp2, const float* __restrict__ b1,
            const float* __restrict__ b2) {
    __shared__ short sW[16384];
    __shared__ short sA[16384];
    const int t = threadIdx.x, wv = t >> 6, lane = t & 63;
    const int row0 = blockIdx.x * 128;
    ACC_INIT;

    stage_a(hB, sA, row0, wv, lane);
    stage_w(Wp1, sW, wv, lane);
    drain_barrier();
    mm_tile(sA, sW, wv, lane, acc0, acc1);
    __syncthreads();
    act_to_lds(sA, b1, wv, lane, acc0, acc1);
    stage_w(Wp2, sW, wv, lane);
    drain_barrier();
    mm_tile(sA, sW, wv, lane, acc0, acc1);

    const int m = lane & 15, g = lane >> 4;
    const int rowbase = row0 + wv * 32 + g * 4;
    float bb[8];
#pragma unroll
    for (int cb = 0; cb < 8; ++cb) bb[cb] = b2[cb * 16 + m];
#pragma unroll
    for (int f = 0; f < 2; ++f)
#pragma unroll
        for (int cb = 0; cb < 8; ++cb)
#pragma unroll
            for (int rr = 0; rr < 4; ++rr) {
                int R = rowbase + f * 16 + rr;
                if (R < NN)
                    hB[(size_t)R * 128 + cb * 16 + m] =
                        f2bf((f ? acc1[cb][rr] : acc0[cb][rr]) + bb[cb]);
            }
}

// x2 = ELU(ELU(ELU(h@Wself+agg@Wneigh+bc)@Wsi1+bs1)@Wsi2+bs2) -> B1 (bf16)
__global__ __launch_bounds__(256)
void k_sage_si(const unsigned short* __restrict__ hB, const unsigned short* __restrict__ AG,
               const short* __restrict__ WpSelf, const short* __restrict__ WpNeigh,
               const short* __restrict__ WpSi1, const short* __restrict__ WpSi2,
               const float* __restrict__ bc, const float* __restrict__ bs1,
               const float* __restrict__ bs2, unsigned short* __restrict__ B1out) {
    __shared__ short sW[16384];
    __shared__ short sA[16384];
    const int t = threadIdx.x, wv = t >> 6, lane = t & 63;
    const int row0 = blockIdx.x * 128;
    ACC_INIT;

    stage_a(hB, sA, row0, wv, lane);
    stage_w(WpSelf, sW, wv, lane);
    drain_barrier();
    mm_tile(sA, sW, wv, lane, acc0, acc1);
    __syncthreads();

    stage_a(AG, sA, row0, wv, lane);
    stage_w(WpNeigh, sW, wv, lane);
    drain_barrier();
    mm_tile(sA, sW, wv, lane, acc0, acc1);   // accumulate
    __syncthreads();

    act_to_lds(sA, bc, wv, lane, acc0, acc1);
    stage_w(WpSi1, sW, wv, lane);
    drain_barrier();
    mm_tile(sA, sW, wv, lane, acc0, acc1);
    __syncthreads();

    act_to_lds(sA, bs1, wv, lane, acc0, acc1);
    stage_w(WpSi2, sW, wv, lane);
    drain_barrier();
    mm_tile(sA, sW, wv, lane, acc0, acc1);

    const int m = lane & 15, g = lane >> 4;
    const int rowbase = row0 + wv * 32 + g * 4;
    float bb[8];
#pragma unroll
    for (int cb = 0; cb < 8; ++cb) bb[cb] = bs2[cb * 16 + m];
#pragma unroll
    for (int f = 0; f < 2; ++f)
#pragma unroll
        for (int cb = 0; cb < 8; ++cb)
#pragma unroll
            for (int rr = 0; rr < 4; ++rr) {
                int R = rowbase + f * 16 + rr;
                if (R < NN) {
                    float v = (f ? acc1[cb][rr] : acc0[cb][rr]) + bb[cb];
                    v = (v > 0.f) ? v : expm1f(v);
                    B1out[(size_t)R * 128 + cb * 16 + m] = f2bf(v);
                }
            }
}

// out = x2@Wself2 + agg@Wneigh2 + b + h_skip   (f32 out)
__global__ __launch_bounds__(256)
void k_conv2(const unsigned short* __restrict__ B1, const unsigned short* __restrict__ AG,
             const unsigned short* __restrict__ HS, const short* __restrict__ WpSelf,
             const short* __restrict__ WpNeigh, const float* __restrict__ bias,
             float* __restrict__ out) {
    __shared__ short sW[16384];
    __shared__ short sA[16384];
    const int t = threadIdx.x, wv = t >> 6, lane = t & 63;
    const int row0 = blockIdx.x * 128;
    ACC_INIT;

    stage_a(B1, sA, row0, wv, lane);
    stage_w(WpSelf, sW, wv, lane);
    drain_barrier();
    mm_tile(sA, sW, wv, lane, acc0, acc1);
    __syncthreads();

    stage_a(AG, sA, row0, wv, lane);
    stage_w(WpNeigh, sW, wv, lane);
    drain_barrier();
    mm_tile(sA, sW, wv, lane, acc0, acc1);

    const int m = lane & 15, g = lane >> 4;
    const int rowbase = row0 + wv * 32 + g * 4;
    float bb[8];
#pragma unroll
    for (int cb = 0; cb < 8; ++cb) bb[cb] = bias[cb * 16 + m];
#pragma unroll
    for (int f = 0; f < 2; ++f)
#pragma unroll
        for (int cb = 0; cb < 8; ++cb)
#pragma unroll
            for (int rr = 0; rr < 4; ++rr) {
                int R = rowbase + f * 16 + rr;
                if (R < NN) {
                    size_t idx = (size_t)R * 128 + cb * 16 + m;
                    out[idx] = (f ? acc1[cb][rr] : acc0[cb][rr]) + bb[cb] + bf2f(HS[idx]);
                }
            }
}

// ---------------- launch ----------------

extern "C" void kernel_launch(void* const* d_in, const int* in_sizes, int n_in,
                              void* d_out, int out_size, void* d_ws, size_t ws_size,
                              hipStream_t stream) {
    const float* h        = (const float*)d_in[0];
    const int*   src      = (const int*)d_in[1];
    const int*   dst      = (const int*)d_in[2];
    const float* W_skip1  = (const float*)d_in[3];
    const float* b_skip1  = (const float*)d_in[4];
    const float* W_skip2  = (const float*)d_in[5];
    const float* b_skip2  = (const float*)d_in[6];
    const float* W_self1  = (const float*)d_in[7];
    const float* W_neigh1 = (const float*)d_in[8];
    const float* b_conv1  = (const float*)d_in[9];
    const float* W_si1    = (const float*)d_in[10];
    const float* b_si1    = (const float*)d_in[11];
    const float* W_si2    = (const float*)d_in[12];
    const float* b_si2    = (const float*)d_in[13];
    const float* W_self2  = (const float*)d_in[14];
    const float* W_neigh2 = (const float*)d_in[15];
    const float* b_conv2  = (const float*)d_in[16];
    float* out = (float*)d_out;

    char* ws = (char*)d_ws;
    int* deg       = (int*)ws;            // [50048]
    int* cursor    = deg + 50048;         // [50048]
    int* row_start = deg + 100096;        // [50001] (padded region to 150208)
    int* partials  = deg + 150208;        // [64]
    int* col_idx   = deg + 150272;        // [800000]  -> ends at byte 3801088
    short* wpk          = (short*)(ws + 3801088);            // 8 x 16384 bf16 = 256 KB
    unsigned short* hB  = (unsigned short*)(ws + 4063232);   // 6.4M bf16 (h, later h_skip)
    unsigned short* B1  = (unsigned short*)(ws + 16863232);  // 6.4M bf16
    unsigned short* B2  = (unsigned short*)(ws + 29663232);  // 6.4M bf16

    hipMemsetAsync(ws, 0, 100096 * sizeof(int), stream);

    k_hist<<<(NE + 255) / 256, 256, 0, stream>>>(dst, deg);
    k_scan_part<<<49, 1024, 0, stream>>>(deg, partials);
    k_scan_top<<<1, 64, 0, stream>>>(partials, row_start, 49);
    k_scan_final<<<49, 1024, 0, stream>>>(deg, partials, row_start);
    k_scatter<<<(NE + 255) / 256, 256, 0, stream>>>(src, dst, row_start, cursor, col_idx);

    k_packW<<<8, 256, 0, stream>>>(W_skip1, W_skip2, W_self1, W_neigh1,
                                   W_si1, W_si2, W_self2, W_neigh2, wpk);
    k_cvt<<<3125, 256, 0, stream>>>(h, hB);

    const int GB = (NN + 127) / 128;  // 391

    // SAGE1 agg (reads hB before it's overwritten by skip)
    k_agg<<<(NN * 64) / 256 + 1, 256, 0, stream>>>(hB, row_start, col_idx, B2);

    // conv1 + si MLP fused: B1 = x2
    k_sage_si<<<GB, 256, 0, stream>>>(hB, B2, wpk + 2 * 16384, wpk + 3 * 16384,
                                      wpk + 4 * 16384, wpk + 5 * 16384,
                                      b_conv1, b_si1, b_si2, B1);

    // skip MLP fused, in-place hB -> h_skip (bf16)
    k_skip<<<GB, 256, 0, stream>>>(hB, wpk, wpk + 16384, b_skip1, b_skip2);

    // SAGE2 agg on x2
    k_agg<<<(NN * 64) / 256 + 1, 256, 0, stream>>>(B1, row_start, col_idx, B2);

    // conv2 + residual
    k_conv2<<<GB, 256, 0, stream>>>(B1, B2, hB, wpk + 6 * 16384, wpk + 7 * 16384,
                                    b_conv2, out);
}